// Round 1
// baseline (826.773 us; speedup 1.0000x reference)
//
#include <hip/hip_runtime.h>
#include <math.h>

#define B_   32
#define H_   56      // spatial side
#define NH   8       // heads
#define HD   32      // head dim
#define WS_  4       // window side
#define T_   16      // tokens per window
#define DM   256     // model dim
#define DQKV 768
#define NW   14      // windows per side

// One block per (batch, window). 256 threads = 4 waves.
// LDS: xs 16KB + qkvs 48KB + att 8KB = 72KB -> 2 blocks/CU.
__global__ __launch_bounds__(256, 2)
void swin_fused(const float* __restrict__ x,
                const float* __restrict__ W,
                const float* __restrict__ bias,
                float* __restrict__ out)
{
    __shared__ float xs[T_][DM];
    __shared__ float qkvs[T_][DQKV];
    __shared__ float att_s[NH][T_][T_];

    const int blk = blockIdx.x;           // 0..6271
    const int b   = blk / (NW * NW);
    const int wj  = blk % NW;
    const int wi  = (blk / NW) % NW;
    const int tid = threadIdx.x;

    // ---------- phase 1: load x tile (with shift-roll fold) ----------
    {
        const int t   = tid >> 4;         // token 0..15
        const int seg = tid & 15;         // 16-float segment
        const int m1 = t >> 2, m2 = t & 3;
        const int gr = (wi * WS_ + m1 + 2) % H_;
        const int gc = (wj * WS_ + m2 + 2) % H_;
        const float* xrow = x + ((size_t)b * (H_ * H_) + (size_t)gr * H_ + gc) * DM;
        const float4* src = (const float4*)(xrow + seg * 16);
        float4* dst = (float4*)(&xs[t][seg * 16]);
        #pragma unroll
        for (int c = 0; c < 4; ++c) dst[c] = src[c];
    }
    __syncthreads();

    // ---------- phase 2: qkv[16][768] = xs @ W + b ----------
    // thread owns columns {tid, tid+256, tid+512} x all 16 tokens
    {
        float acc[3][T_];
        #pragma unroll
        for (int c = 0; c < 3; ++c) {
            const float bv = bias[tid + 256 * c];
            #pragma unroll
            for (int t = 0; t < T_; ++t) acc[c][t] = bv;
        }
        #pragma unroll 4
        for (int k = 0; k < DM; ++k) {
            float wv[3];
            #pragma unroll
            for (int c = 0; c < 3; ++c)
                wv[c] = W[(size_t)k * DQKV + tid + 256 * c];
            #pragma unroll
            for (int t = 0; t < T_; ++t) {
                const float xv = xs[t][k];   // wave-broadcast LDS read
                #pragma unroll
                for (int c = 0; c < 3; ++c)
                    acc[c][t] = fmaf(xv, wv[c], acc[c][t]);
            }
        }
        #pragma unroll
        for (int c = 0; c < 3; ++c)
            #pragma unroll
            for (int t = 0; t < T_; ++t)
                qkvs[t][tid + 256 * c] = acc[c][t];
    }
    __syncthreads();

    // ---------- phase 3: scores + mask + softmax ----------
    // 8 heads x 32 threads; thread j: row t=j>>1, s-half (j&1)*8
    const int h  = tid >> 5;
    const int j  = tid & 31;
    const int t  = j >> 1;
    const int sh = (j & 1) * 8;
    const float scale = 0.17677669529663687f;  // 1/sqrt(32)

    {
        float qreg[HD];
        #pragma unroll
        for (int e = 0; e < HD; ++e) qreg[e] = qkvs[t][h * 96 + e * 3 + 0];
        float sc[8];
        #pragma unroll
        for (int ss = 0; ss < 8; ++ss) {
            const int s = sh + ss;
            float a = 0.f;
            #pragma unroll
            for (int e = 0; e < HD; ++e)
                a = fmaf(qreg[e], qkvs[s][h * 96 + e * 3 + 1], a);
            sc[ss] = a * scale;
        }
        // shifted-window masks
        const bool lastrow = (wi == NW - 1);
        const bool lastcol = (wj == NW - 1);
        if (lastrow || lastcol) {
            #pragma unroll
            for (int ss = 0; ss < 8; ++ss) {
                const int s = sh + ss;
                bool m = false;
                if (lastrow && ((t >= 8) != (s >= 8))) m = true;
                if (lastcol && (((t & 3) >= 2) != ((s & 3) >= 2))) m = true;
                if (m) sc[ss] = -1e30f;
            }
        }
        // softmax over the 16-wide row (this thread has 8, partner lane^1 has 8)
        float mx = sc[0];
        #pragma unroll
        for (int ss = 1; ss < 8; ++ss) mx = fmaxf(mx, sc[ss]);
        mx = fmaxf(mx, __shfl_xor(mx, 1));
        float sum = 0.f;
        #pragma unroll
        for (int ss = 0; ss < 8; ++ss) { sc[ss] = __expf(sc[ss] - mx); sum += sc[ss]; }
        sum += __shfl_xor(sum, 1);
        const float inv = 1.0f / sum;
        #pragma unroll
        for (int ss = 0; ss < 8; ++ss) att_s[h][t][sh + ss] = sc[ss] * inv;
    }
    __syncthreads();

    // ---------- phase 4: out[t][e] = sum_s att[t][s] * v[s][e]; store ----------
    {
        const int eoff = (j & 1) * 16;   // thread covers 16 e's of row t
        float areg[T_];
        #pragma unroll
        for (int s = 0; s < T_; ++s) areg[s] = att_s[h][t][s];
        float o[16];
        #pragma unroll
        for (int ee = 0; ee < 16; ++ee) o[ee] = 0.f;
        #pragma unroll
        for (int s = 0; s < T_; ++s) {
            #pragma unroll
            for (int ee = 0; ee < 16; ++ee)
                o[ee] = fmaf(areg[s], qkvs[s][h * 96 + (eoff + ee) * 3 + 2], o[ee]);
        }
        const int m1 = t >> 2, m2 = t & 3;
        const int gr = (wi * WS_ + m1 + 2) % H_;
        const int gc = (wj * WS_ + m2 + 2) % H_;
        float* orow = out + ((size_t)b * (H_ * H_) + (size_t)gr * H_ + gc) * DM + h * HD + eoff;
        #pragma unroll
        for (int ee = 0; ee < 16; ee += 4) {
            float4 v4 = make_float4(o[ee], o[ee + 1], o[ee + 2], o[ee + 3]);
            *(float4*)(orow + ee) = v4;
        }
    }
}

extern "C" void kernel_launch(void* const* d_in, const int* in_sizes, int n_in,
                              void* d_out, int out_size, void* d_ws, size_t ws_size,
                              hipStream_t stream) {
    const float* x    = (const float*)d_in[0];
    const float* W    = (const float*)d_in[1];
    const float* bias = (const float*)d_in[2];
    float* out = (float*)d_out;
    (void)d_ws; (void)ws_size; (void)in_sizes; (void)n_in; (void)out_size;

    const int nblocks = B_ * NW * NW;   // 6272
    swin_fused<<<nblocks, 256, 0, stream>>>(x, W, bias, out);
}

// Round 2
// 354.822 us; speedup vs baseline: 2.3301x; 2.3301x over previous
//
#include <hip/hip_runtime.h>

typedef __attribute__((ext_vector_type(8))) short short8;
typedef __attribute__((ext_vector_type(4))) float floatx4;

#define NWSIDE 14        // windows per side
#define HLEN   56        // spatial side
#define DM     256       // model dim
#define NHEADS 8
#define HDIM   32
#define T_     16        // tokens per window

// LDS qkv layout: [win(4)][token(16)][col], col = head*104 + sect*32 + e
// row stride 840 bf16 (16B aligned; quad rows land on disjoint bank quartets)
#define ROWSTRIDE 840
#define WINSTRIDE (T_ * ROWSTRIDE)   // 13440 bf16

static __device__ __forceinline__ unsigned short f2bf(float f) {
    unsigned int u = __float_as_uint(f);
    unsigned int r = (u + 0x7fffu + ((u >> 16) & 1u)) >> 16;   // RNE
    return (unsigned short)r;
}
static __device__ __forceinline__ float bf2f(unsigned short h) {
    return __uint_as_float(((unsigned int)h) << 16);
}

// ---- prep: W (fp32 [256][768]) -> Wt bf16 [col'][k], col-permuted; bias' ----
// col' = h*96 + sect*32 + e  <-  orig col = h*96 + e*3 + sect
__global__ void swin_prep(const float* __restrict__ W, const float* __restrict__ bias,
                          unsigned short* __restrict__ Wt, float* __restrict__ bperm) {
    int idx = blockIdx.x * 256 + threadIdx.x;       // 0..196607
    int cp = idx >> 8;                               // col' 0..767
    int k  = idx & 255;
    int h = cp / 96, r = cp % 96;
    int sect = r >> 5, e = r & 31;
    int c = h * 96 + e * 3 + sect;
    Wt[idx] = f2bf(W[(size_t)k * 768 + c]);
    if (k == 0) bperm[cp] = bias[c];
}

static __device__ __forceinline__ void load_b(const unsigned short* __restrict__ Wt,
                                              int t, int lrow, int lq, short8* B) {
    const unsigned short* wp = Wt + ((size_t)(t * 16 + lrow)) * 256 + lq * 8;
    #pragma unroll
    for (int ks = 0; ks < 8; ++ks)
        B[ks] = *(const short8*)(wp + ks * 32);
}

// 1568 blocks (32 batches x 49 window-groups), 256 threads = 4 waves.
// Wave v: GEMM for n-tiles [12v,12v+12) over all 4 windows; attention for window v.
__global__ __launch_bounds__(256, 1)
void swin_mfma(const float* __restrict__ x,
               const unsigned short* __restrict__ Wt,
               const float* __restrict__ bperm,
               float* __restrict__ out) {
    __shared__ unsigned short qkvs[4 * WINSTRIDE];   // 107,520 B

    const int blk = blockIdx.x;
    const int b   = blk / 49;
    const int g   = blk % 49;                        // window group: windows 4g..4g+3
    const int tid = threadIdx.x;
    const int wv  = tid >> 6;                        // wave 0..3
    const int lane = tid & 63;
    const int lrow = lane & 15;                      // MFMA m/n lane index
    const int lq   = lane >> 4;                      // quad

    // ---------------- A fragments: x -> bf16, 4 windows ----------------
    short8 A[4][8];
    #pragma unroll
    for (int w = 0; w < 4; ++w) {
        const int ww = g * 4 + w;
        const int wi = ww / NWSIDE, wj = ww % NWSIDE;
        const int gr = (wi * 4 + (lrow >> 2) + 2) % HLEN;
        const int gc = (wj * 4 + (lrow & 3) + 2) % HLEN;
        const float* xp = x + ((size_t)(b * 3136 + gr * 56 + gc)) * DM + lq * 8;
        #pragma unroll
        for (int ks = 0; ks < 8; ++ks) {
            floatx4 f0 = *(const floatx4*)(xp + ks * 32);
            floatx4 f1 = *(const floatx4*)(xp + ks * 32 + 4);
            short8 a;
            a[0] = (short)f2bf(f0[0]); a[1] = (short)f2bf(f0[1]);
            a[2] = (short)f2bf(f0[2]); a[3] = (short)f2bf(f0[3]);
            a[4] = (short)f2bf(f1[0]); a[5] = (short)f2bf(f1[1]);
            a[6] = (short)f2bf(f1[2]); a[7] = (short)f2bf(f1[3]);
            A[w][ks] = a;
        }
    }

    // ---------------- GEMM: 12 n-tiles, B double-buffered ----------------
    short8 Bc[8], Bn[8];
    load_b(Wt, wv * 12, lrow, lq, Bc);
    #pragma unroll
    for (int n = 0; n < 12; ++n) {
        const int t = wv * 12 + n;
        if (n + 1 < 12) load_b(Wt, t + 1, lrow, lq, Bn);
        const float bv = bperm[t * 16 + lrow];
        floatx4 acc[4];
        #pragma unroll
        for (int w = 0; w < 4; ++w) {
            floatx4 a0; a0[0] = bv; a0[1] = bv; a0[2] = bv; a0[3] = bv;
            acc[w] = a0;
        }
        #pragma unroll
        for (int ks = 0; ks < 8; ++ks)
            #pragma unroll
            for (int w = 0; w < 4; ++w)
                acc[w] = __builtin_amdgcn_mfma_f32_16x16x32_bf16(A[w][ks], Bc[ks], acc[w], 0, 0, 0);
        // flush tile to LDS (bf16). lds col = col' + 8*head
        const int ldsc = t * 16 + (t / 6) * 8 + lrow;
        #pragma unroll
        for (int w = 0; w < 4; ++w)
            #pragma unroll
            for (int i = 0; i < 4; ++i)
                qkvs[w * WINSTRIDE + (lq * 4 + i) * ROWSTRIDE + ldsc] = f2bf(acc[w][i]);
        if (n + 1 < 12) {
            #pragma unroll
            for (int ks = 0; ks < 8; ++ks) Bc[ks] = Bn[ks];
        }
    }
    __syncthreads();

    // ---------------- attention: wave wv handles window wv ----------------
    const int h = lane >> 3;            // head
    const int p = lane & 7;             // row-pair index: rows 2p, 2p+1
    const int t0 = 2 * p, t1 = 2 * p + 1;
    const int ww = g * 4 + wv;
    const int wi = ww / NWSIDE, wj = ww % NWSIDE;
    const bool lastrow = (wi == NWSIDE - 1);
    const bool lastcol = (wj == NWSIDE - 1);
    const bool t_half = (p >= 4);       // t>=8 (same for t0,t1)
    const bool t_col2 = (p & 1);        // (t&3)>=2 (same for t0,t1)
    const unsigned short* qk = qkvs + wv * WINSTRIDE;
    const float scale = 0.17677669529663687f;   // 1/sqrt(32)

    // q rows (scale folded in)
    float q0[32], q1[32];
    #pragma unroll
    for (int ch = 0; ch < 4; ++ch) {
        short8 s0 = *(const short8*)(qk + t0 * ROWSTRIDE + h * 104 + ch * 8);
        short8 s1 = *(const short8*)(qk + t1 * ROWSTRIDE + h * 104 + ch * 8);
        #pragma unroll
        for (int j = 0; j < 8; ++j) {
            q0[ch * 8 + j] = bf2f((unsigned short)s0[j]) * scale;
            q1[ch * 8 + j] = bf2f((unsigned short)s1[j]) * scale;
        }
    }

    // scores + mask
    float att0[16], att1[16];
    #pragma unroll
    for (int s = 0; s < 16; ++s) {
        float d0 = 0.f, d1 = 0.f;
        #pragma unroll
        for (int ch = 0; ch < 4; ++ch) {
            short8 kv = *(const short8*)(qk + s * ROWSTRIDE + h * 104 + 32 + ch * 8);
            #pragma unroll
            for (int j = 0; j < 8; ++j) {
                float kf = bf2f((unsigned short)kv[j]);
                d0 = fmaf(q0[ch * 8 + j], kf, d0);
                d1 = fmaf(q1[ch * 8 + j], kf, d1);
            }
        }
        bool m = false;
        if (lastrow && (t_half != (s >= 8))) m = true;
        if (lastcol && (t_col2 != ((s & 3) >= 2))) m = true;
        if (m) { d0 = -1e30f; d1 = -1e30f; }
        att0[s] = d0; att1[s] = d1;
    }

    // softmax fully in-lane
    float mx0 = att0[0], mx1 = att1[0];
    #pragma unroll
    for (int s = 1; s < 16; ++s) { mx0 = fmaxf(mx0, att0[s]); mx1 = fmaxf(mx1, att1[s]); }
    float sum0 = 0.f, sum1 = 0.f;
    #pragma unroll
    for (int s = 0; s < 16; ++s) {
        att0[s] = __expf(att0[s] - mx0); sum0 += att0[s];
        att1[s] = __expf(att1[s] - mx1); sum1 += att1[s];
    }
    const float inv0 = 1.0f / sum0, inv1 = 1.0f / sum1;
    #pragma unroll
    for (int s = 0; s < 16; ++s) { att0[s] *= inv0; att1[s] *= inv1; }

    // PV + store
    const int gr0 = (wi * 4 + (t0 >> 2) + 2) % HLEN;
    const int gc0 = (wj * 4 + (t0 & 3) + 2) % HLEN;
    const int gr1 = (wi * 4 + (t1 >> 2) + 2) % HLEN;
    const int gc1 = (wj * 4 + (t1 & 3) + 2) % HLEN;
    float* op0 = out + ((size_t)(b * 3136 + gr0 * 56 + gc0)) * DM + h * HDIM;
    float* op1 = out + ((size_t)(b * 3136 + gr1 * 56 + gc1)) * DM + h * HDIM;
    #pragma unroll
    for (int ec = 0; ec < 4; ++ec) {
        float o0[8], o1[8];
        #pragma unroll
        for (int j = 0; j < 8; ++j) { o0[j] = 0.f; o1[j] = 0.f; }
        #pragma unroll
        for (int s = 0; s < 16; ++s) {
            short8 vv = *(const short8*)(qk + s * ROWSTRIDE + h * 104 + 64 + ec * 8);
            #pragma unroll
            for (int j = 0; j < 8; ++j) {
                float vf = bf2f((unsigned short)vv[j]);
                o0[j] = fmaf(att0[s], vf, o0[j]);
                o1[j] = fmaf(att1[s], vf, o1[j]);
            }
        }
        floatx4 v0a; v0a[0] = o0[0]; v0a[1] = o0[1]; v0a[2] = o0[2]; v0a[3] = o0[3];
        floatx4 v0b; v0b[0] = o0[4]; v0b[1] = o0[5]; v0b[2] = o0[6]; v0b[3] = o0[7];
        floatx4 v1a; v1a[0] = o1[0]; v1a[1] = o1[1]; v1a[2] = o1[2]; v1a[3] = o1[3];
        floatx4 v1b; v1b[0] = o1[4]; v1b[1] = o1[5]; v1b[2] = o1[6]; v1b[3] = o1[7];
        *(floatx4*)(op0 + ec * 8)     = v0a;
        *(floatx4*)(op0 + ec * 8 + 4) = v0b;
        *(floatx4*)(op1 + ec * 8)     = v1a;
        *(floatx4*)(op1 + ec * 8 + 4) = v1b;
    }
}

extern "C" void kernel_launch(void* const* d_in, const int* in_sizes, int n_in,
                              void* d_out, int out_size, void* d_ws, size_t ws_size,
                              hipStream_t stream) {
    const float* x    = (const float*)d_in[0];
    const float* W    = (const float*)d_in[1];
    const float* bias = (const float*)d_in[2];
    float* out = (float*)d_out;
    (void)in_sizes; (void)n_in; (void)out_size;

    unsigned short* Wt = (unsigned short*)d_ws;                      // 768*256*2 = 393216 B
    float* bperm = (float*)((char*)d_ws + 768 * 256 * 2);            // +3072 B

    swin_prep<<<768, 256, 0, stream>>>(W, bias, Wt, bperm);
    swin_mfma<<<32 * 49, 256, 0, stream>>>(x, Wt, bperm, out);
}